// Round 3
// baseline (8736.764 us; speedup 1.0000x reference)
//
#include <hip/hip_runtime.h>

typedef _Float16 f16;
typedef _Float16 f16x8 __attribute__((ext_vector_type(8)));
typedef float f32x4 __attribute__((ext_vector_type(4)));
typedef unsigned short ushort_t;

// ---------------------------------------------------------------------------
// PoseConvLSTM, single persistent kernel. 129 phases; phase ph computes
// layer1[t=ph] and layer2[t=ph-1] concurrently (independent given h1[ph-1]),
// separated by a device-scope two-level grid barrier.
//
// Numerics: split-fp16 (hi+lo), 3 MFMAs per product (~fp32 accuracy).
// State buffers (ws, f16 bits), padded-transposed [66][66][C]:
//   in1[par] C=48: c0-2=x[t], c3-34=h1prev, c35-47=0
//   in2[par] C=96: c0-31=h1[t], c32-95=h2prev
// d_out (floats): pose[768] | h1[131072] | c1[131072] | h2[262144] | c2[262144]
// ---------------------------------------------------------------------------

#define IN1SZ 209088  // 66*66*48
#define IN2SZ 418176  // 66*66*96
#define WP1OFF 2509056
#define WP1SZ 147456  // 2mb*18s*4mt*2hl*512
#define WP2OFF (WP1OFF + WP1SZ)
#define WP2SZ 442368  // 2mb*27s*8mt*2hl*512
#define BAROFF (WP2OFF + WP2SZ)  // ushort offset of barrier ints (zeroed each call)
#define NPH 129

__device__ __forceinline__ float sigm(float x) { return 1.0f / (1.0f + __expf(-x)); }
__device__ __forceinline__ ushort_t f2u(f16 v) { return __builtin_bit_cast(ushort_t, v); }
__device__ __forceinline__ f16x8 u2f(uint4 v) { return __builtin_bit_cast(f16x8, v); }

// ---- init: pack weights into MFMA A-fragment order, pose=fc_b, stage x[0] ----
__global__ __launch_bounds__(256) void pack_kernel(const float* __restrict__ w1,
                                                   const float* __restrict__ w2,
                                                   const float* __restrict__ fcb,
                                                   const float* __restrict__ x0,
                                                   float* __restrict__ pose,
                                                   ushort_t* __restrict__ wp1,
                                                   ushort_t* __restrict__ wp2,
                                                   ushort_t* __restrict__ in1hi0,
                                                   ushort_t* __restrict__ in1lo0) {
  int i = blockIdx.x * 256 + threadIdx.x;
  if (i < 55296) {  // wp2
    int lane = i & 63;
    int r0 = i >> 6;
    int hl = r0 & 1;
    int f = r0 >> 1;  // (mb*27+s)*8+mt
    int mt = f & 7;
    int sm = f >> 3;
    int s = sm % 27, mb = sm / 27;
    int m = mt * 16 + (lane & 15);
    int rg = mb * 128 + m;
    int h = rg >> 2, G = rg & 3;
    int orow = G * 64 + h;
    int tap = s / 3, cb = (s % 3) * 32;
    int cq = cb + (lane >> 4) * 8;
    for (int j = 0; j < 8; ++j) {
      float v = w2[(orow * 96 + cq + j) * 9 + tap];
      f16 vh = (f16)v;
      f16 vl = (f16)(v - (float)vh);
      wp2[(f * 2 + hl) * 512 + lane * 8 + j] = f2u(hl ? vl : vh);
    }
    return;
  }
  i -= 55296;
  if (i < 18432) {  // wp1
    int lane = i & 63;
    int r0 = i >> 6;
    int hl = r0 & 1;
    int f = r0 >> 1;  // (mb*18+s)*4+mt
    int mt = f & 3;
    int sm = f >> 2;
    int s = sm % 18, mb = sm / 18;
    int m = mt * 16 + (lane & 15);
    int rg = mb * 64 + m;
    int h = rg >> 2, G = rg & 3;
    int orow = G * 32 + h;
    int tap = s >> 1, cb = (s & 1) * 32;
    int cq = cb + (lane >> 4) * 8;
    for (int j = 0; j < 8; ++j) {
      int c = cq + j;
      float v = (c < 35) ? w1[(orow * 35 + c) * 9 + tap] : 0.f;
      f16 vh = (f16)v;
      f16 vl = (f16)(v - (float)vh);
      wp1[(f * 2 + hl) * 512 + lane * 8 + j] = f2u(hl ? vl : vh);
    }
    return;
  }
  i -= 18432;
  if (i < 768) {
    pose[i] = fcb[i % 6];
    return;
  }
  i -= 768;
  if (i < 12288) {  // x[0] -> in1[0] c0-2
    int c = i >> 12, pix = i & 4095;
    int y = pix >> 6, x = pix & 63;
    float v = x0[i];
    f16 vh = (f16)v;
    f16 vl = (f16)(v - (float)vh);
    int pidx = ((y + 1) * 66 + (x + 1)) * 48 + c;
    in1hi0[pidx] = f2u(vh);
    in1lo0[pidx] = f2u(vl);
  }
}

#define MFMA(a, b, c) __builtin_amdgcn_mfma_f32_16x16x32_f16((a), (b), (c), 0, 0, 0)

__global__ __launch_bounds__(256) void persist(
    const float* __restrict__ input, const ushort_t* __restrict__ wp1,
    const ushort_t* __restrict__ wp2, const float* __restrict__ b1g,
    const float* __restrict__ b2g, const float* __restrict__ fcw, float* __restrict__ pose,
    float* __restrict__ h1o, float* __restrict__ c1o, float* __restrict__ h2o,
    float* __restrict__ c2o, ushort_t* i1h0, ushort_t* i1h1, ushort_t* i1l0, ushort_t* i1l1,
    ushort_t* i2h0, ushort_t* i2h1, ushort_t* i2l0, ushort_t* i2l1, int* bars) {
  // LDS: 41.6K (L2 halo) + 28.8K (L1 halo) + pad to force 1 block/CU (~82.8 KB)
  __shared__ __align__(16) ushort_t BH2[100 * 104], BL2[100 * 104];
  __shared__ __align__(16) ushort_t BH1[100 * 72], BL1[100 * 72];
  __shared__ float red[4][6];
  __shared__ ushort_t ldspad[6144];

  const int tid = threadIdx.x, blk = blockIdx.x;
  if (tid == 0) ((volatile ushort_t*)ldspad)[0] = 0;  // keep pad alive
  const int lane = tid & 63, w = tid >> 6;
  const int q = lane >> 4, n = lane & 15, py = n >> 3, px = n & 7;
  const int mbx = blk & 3;   // layer2: rows [mbx*64..); layer1: rows [mbx*32..)
  const int nc = blk >> 2;   // 0..63: 8x8-px tile
  const int Y0 = (nc >> 3) * 8, X0 = (nc & 7) * 8;
  const int mt0 = (w & 1) * 2;   // layer2: wave's 2 m-tiles
  const int nt0 = (w >> 1) * 2;  // both: wave's 2 n-tiles
  const int mtl1 = w & 1;        // layer1: wave's single m-tile

  ushort_t* in1h[2] = {i1h0, i1h1};
  ushort_t* in1l[2] = {i1l0, i1l1};
  ushort_t* in2h[2] = {i2h0, i2h1};
  ushort_t* in2l[2] = {i2l0, i2l1};

  // A-fragment base pointers (phase-invariant)
  const ushort_t *a2B0, *a2B1, *a1B;
  {
    int rt = mbx * 4 + mt0;
    a2B0 = wp2 + (size_t)((rt >> 3) * 216 + (rt & 7)) * 1024 + lane * 8;
    rt++;
    a2B1 = wp2 + (size_t)((rt >> 3) * 216 + (rt & 7)) * 1024 + lane * 8;
    rt = mbx * 2 + mtl1;
    a1B = wp1 + (size_t)((rt >> 2) * 72 + (rt & 3)) * 1024 + lane * 8;
  }
  // B LDS base offsets (ushort index), per n-tile
  const int bO20 = (((nt0 + 0) * 2 + py) * 10 + px) * 104 + q * 8;
  const int bO21 = (((nt0 + 1) * 2 + py) * 10 + px) * 104 + q * 8;
  const int bO10 = (((nt0 + 0) * 2 + py) * 10 + px) * 72 + q * 8;
  const int bO11 = (((nt0 + 1) * 2 + py) * 10 + px) * 72 + q * 8;

  for (int ph = 0; ph < NPH; ++ph) {
    const int t1 = ph, t2 = ph - 1;
    const int p = ph & 1, pn = p ^ 1;
    const bool doL2 = (t2 >= 0), doL1 = (t1 < 128);

    // ---- stage halos into LDS ----
    if (doL2) {
      const ushort_t* sh = in2h[pn];  // parity (ph-1)&1 == pn
      const ushort_t* sl = in2l[pn];
      for (int i = tid; i < 1200; i += 256) {
        int pos = i / 12, c8 = (i % 12) * 8;
        int hy = pos / 10, hx = pos % 10;
        int src = ((Y0 + hy) * 66 + (X0 + hx)) * 96 + c8;
        int dst = pos * 104 + c8;
        *(uint4*)&BH2[dst] = *(const uint4*)&sh[src];
        *(uint4*)&BL2[dst] = *(const uint4*)&sl[src];
      }
    }
    if (doL1) {
      const ushort_t* sh = in1h[p];
      const ushort_t* sl = in1l[p];
      for (int i = tid; i < 800; i += 256) {
        int pos = i >> 3, k = i & 7;
        int hy = pos / 10, hx = pos % 10;
        int dst = pos * 72 + k * 8;
        if (k < 6) {
          int src = ((Y0 + hy) * 66 + (X0 + hx)) * 48 + k * 8;
          *(uint4*)&BH1[dst] = *(const uint4*)&sh[src];
          *(uint4*)&BL1[dst] = *(const uint4*)&sl[src];
        } else {  // zero-fill channels 48..63 (A is zero there; avoid NaN garbage)
          *(uint4*)&BH1[dst] = uint4{0, 0, 0, 0};
          *(uint4*)&BL1[dst] = uint4{0, 0, 0, 0};
        }
      }
    }
    __syncthreads();

    // ---- layer 2: M=64/block, N=64/block, K=864; wave: 2mt x 2nt ----
    if (doL2) {
      f32x4 acc00 = {}, acc01 = {}, acc10 = {}, acc11 = {};
      uint4 Ab[2][2][2], Bb[2][2][2];
#pragma unroll
      for (int s0 = 0; s0 < 2; ++s0) {
        Ab[s0][0][0] = *(const uint4*)(a2B0 + s0 * 8192);
        Ab[s0][0][1] = *(const uint4*)(a2B0 + s0 * 8192 + 512);
        Ab[s0][1][0] = *(const uint4*)(a2B1 + s0 * 8192);
        Ab[s0][1][1] = *(const uint4*)(a2B1 + s0 * 8192 + 512);
      }
      Bb[0][0][0] = *(const uint4*)&BH2[bO20];
      Bb[0][0][1] = *(const uint4*)&BL2[bO20];
      Bb[0][1][0] = *(const uint4*)&BH2[bO21];
      Bb[0][1][1] = *(const uint4*)&BL2[bO21];
      int ty = 0, tx = 0, cc = 0;
      for (int s = 0; s < 27; ++s) {
        int ccn = cc + 1, tyn = ty, txn = tx;
        if (ccn == 3) {
          ccn = 0;
          txn++;
          if (txn == 3) { txn = 0; tyn++; }
        }
        uint4 a0h = Ab[s & 1][0][0], a0l = Ab[s & 1][0][1];
        uint4 a1h = Ab[s & 1][1][0], a1l = Ab[s & 1][1][1];
        uint4 b0h = Bb[s & 1][0][0], b0l = Bb[s & 1][0][1];
        uint4 b1h = Bb[s & 1][1][0], b1l = Bb[s & 1][1][1];
        if (s + 2 < 27) {  // A prefetch distance 2
          Ab[s & 1][0][0] = *(const uint4*)(a2B0 + (s + 2) * 8192);
          Ab[s & 1][0][1] = *(const uint4*)(a2B0 + (s + 2) * 8192 + 512);
          Ab[s & 1][1][0] = *(const uint4*)(a2B1 + (s + 2) * 8192);
          Ab[s & 1][1][1] = *(const uint4*)(a2B1 + (s + 2) * 8192 + 512);
        }
        if (s + 1 < 27) {  // B prefetch distance 1
          int d = tyn * 1040 + txn * 104 + ccn * 32;
          Bb[(s + 1) & 1][0][0] = *(const uint4*)&BH2[bO20 + d];
          Bb[(s + 1) & 1][0][1] = *(const uint4*)&BL2[bO20 + d];
          Bb[(s + 1) & 1][1][0] = *(const uint4*)&BH2[bO21 + d];
          Bb[(s + 1) & 1][1][1] = *(const uint4*)&BL2[bO21 + d];
        }
        f16x8 A0h = u2f(a0h), A0l = u2f(a0l), A1h = u2f(a1h), A1l = u2f(a1l);
        f16x8 B0h = u2f(b0h), B0l = u2f(b0l), B1h = u2f(b1h), B1l = u2f(b1l);
        acc00 = MFMA(A0h, B0h, acc00); acc00 = MFMA(A0h, B0l, acc00); acc00 = MFMA(A0l, B0h, acc00);
        acc01 = MFMA(A0h, B1h, acc01); acc01 = MFMA(A0h, B1l, acc01); acc01 = MFMA(A0l, B1h, acc01);
        acc10 = MFMA(A1h, B0h, acc10); acc10 = MFMA(A1h, B0l, acc10); acc10 = MFMA(A1l, B0h, acc10);
        acc11 = MFMA(A1h, B1h, acc11); acc11 = MFMA(A1h, B1l, acc11); acc11 = MFMA(A1l, B1h, acc11);
        ty = tyn; tx = txn; cc = ccn;
      }
      // epilogue: each lane's f32x4 = 4 gates of one (h, pixel)
      float p6[6] = {0, 0, 0, 0, 0, 0};
      ushort_t* dh = in2h[p];
      ushort_t* dl = in2l[p];
#pragma unroll
      for (int mi = 0; mi < 2; ++mi)
#pragma unroll
        for (int ni = 0; ni < 2; ++ni) {
          f32x4 a = mi ? (ni ? acc11 : acc10) : (ni ? acc01 : acc00);
          int h = mbx * 16 + (mt0 + mi) * 4 + q;
          int y = Y0 + (nt0 + ni) * 2 + py, x = X0 + px;
          float zi = a[0] + b2g[0 * 64 + h];
          float zf = a[1] + b2g[1 * 64 + h];
          float zo = a[2] + b2g[2 * 64 + h];
          float zg = a[3] + b2g[3 * 64 + h];
          int cidx = h * 4096 + y * 64 + x;
          float cold = c2o[cidx];
          float cn = sigm(zf) * cold + sigm(zi) * tanhf(zg);
          float hn = sigm(zo) * tanhf(cn);
          c2o[cidx] = cn;
          h2o[cidx] = hn;
          f16 hh = (f16)hn;
          f16 hl = (f16)(hn - (float)hh);
          int pidx = ((y + 1) * 66 + (x + 1)) * 96 + 32 + h;
          dh[pidx] = f2u(hh);
          dl[pidx] = f2u(hl);
#pragma unroll
          for (int j = 0; j < 6; ++j) p6[j] += hn * fcw[j * 262144 + cidx];
        }
#pragma unroll
      for (int j = 0; j < 6; ++j)
#pragma unroll
        for (int off = 32; off; off >>= 1) p6[j] += __shfl_xor(p6[j], off, 64);
      if (lane == 0)
#pragma unroll
        for (int j = 0; j < 6; ++j) red[w][j] = p6[j];
      __syncthreads();
      if (tid < 6)
        atomicAdd(pose + t2 * 6 + tid, red[0][tid] + red[1][tid] + red[2][tid] + red[3][tid]);
    }

    // ---- layer 1: M=32/block, N=64/block, K=576; wave: 1mt x 2nt ----
    if (doL1) {
      f32x4 acc0 = {}, acc1 = {};
      uint4 Ab[2][2], Bb[2][2][2];
#pragma unroll
      for (int s0 = 0; s0 < 2; ++s0) {
        Ab[s0][0] = *(const uint4*)(a1B + s0 * 4096);
        Ab[s0][1] = *(const uint4*)(a1B + s0 * 4096 + 512);
      }
      Bb[0][0][0] = *(const uint4*)&BH1[bO10];
      Bb[0][0][1] = *(const uint4*)&BL1[bO10];
      Bb[0][1][0] = *(const uint4*)&BH1[bO11];
      Bb[0][1][1] = *(const uint4*)&BL1[bO11];
      int ty = 0, tx = 0, cc = 0;
      for (int s = 0; s < 18; ++s) {
        int ccn = cc + 1, tyn = ty, txn = tx;
        if (ccn == 2) {
          ccn = 0;
          txn++;
          if (txn == 3) { txn = 0; tyn++; }
        }
        uint4 ah = Ab[s & 1][0], al = Ab[s & 1][1];
        uint4 b0h = Bb[s & 1][0][0], b0l = Bb[s & 1][0][1];
        uint4 b1h = Bb[s & 1][1][0], b1l = Bb[s & 1][1][1];
        if (s + 2 < 18) {
          Ab[s & 1][0] = *(const uint4*)(a1B + (s + 2) * 4096);
          Ab[s & 1][1] = *(const uint4*)(a1B + (s + 2) * 4096 + 512);
        }
        if (s + 1 < 18) {
          int d = tyn * 720 + txn * 72 + ccn * 32;
          Bb[(s + 1) & 1][0][0] = *(const uint4*)&BH1[bO10 + d];
          Bb[(s + 1) & 1][0][1] = *(const uint4*)&BL1[bO10 + d];
          Bb[(s + 1) & 1][1][0] = *(const uint4*)&BH1[bO11 + d];
          Bb[(s + 1) & 1][1][1] = *(const uint4*)&BL1[bO11 + d];
        }
        f16x8 Ah = u2f(ah), Al = u2f(al);
        f16x8 B0h = u2f(b0h), B0l = u2f(b0l), B1h = u2f(b1h), B1l = u2f(b1l);
        acc0 = MFMA(Ah, B0h, acc0); acc0 = MFMA(Ah, B0l, acc0); acc0 = MFMA(Al, B0h, acc0);
        acc1 = MFMA(Ah, B1h, acc1); acc1 = MFMA(Ah, B1l, acc1); acc1 = MFMA(Al, B1h, acc1);
        ty = tyn; tx = txn; cc = ccn;
      }
      ushort_t* d2h = in2h[p];
      ushort_t* d2l = in2l[p];
      ushort_t* d1h = in1h[pn];
      ushort_t* d1l = in1l[pn];
#pragma unroll
      for (int ni = 0; ni < 2; ++ni) {
        f32x4 a = ni ? acc1 : acc0;
        int h = mbx * 8 + mtl1 * 4 + q;
        int y = Y0 + (nt0 + ni) * 2 + py, x = X0 + px;
        float zi = a[0] + b1g[0 * 32 + h];
        float zf = a[1] + b1g[1 * 32 + h];
        float zo = a[2] + b1g[2 * 32 + h];
        float zg = a[3] + b1g[3 * 32 + h];
        int cidx = h * 4096 + y * 64 + x;
        float cold = c1o[cidx];
        float cn = sigm(zf) * cold + sigm(zi) * tanhf(zg);
        float hn = sigm(zo) * tanhf(cn);
        c1o[cidx] = cn;
        h1o[cidx] = hn;
        f16 hh = (f16)hn;
        f16 hl = (f16)(hn - (float)hh);
        int pb = (y + 1) * 66 + (x + 1);
        d2h[pb * 96 + h] = f2u(hh);  // h1[t] -> in2[p] c0..31
        d2l[pb * 96 + h] = f2u(hl);
        d1h[pb * 48 + 3 + h] = f2u(hh);  // h1[t] -> in1[pn] c3..34
        d1l[pb * 48 + 3 + h] = f2u(hl);
      }
      if (mbx == 0 && t1 < 127 && tid < 192) {  // stage x[t1+1] -> in1[pn] c0..2
        const float* xn = input + (size_t)(t1 + 1) * 12288;
        int pl = tid / 3, c = tid % 3;
        int y = Y0 + (pl >> 3), x = X0 + (pl & 7);
        float v = xn[c * 4096 + y * 64 + x];
        f16 vh = (f16)v;
        f16 vl = (f16)(v - (float)vh);
        int pidx = ((y + 1) * 66 + (x + 1)) * 48 + c;
        d1h[pidx] = f2u(vh);
        d1l[pidx] = f2u(vl);
      }
    }

    // ---- grid barrier (two-level, agent scope) ----
    if (ph + 1 < NPH) {
      __syncthreads();
      if (tid == 0) {
        int* sub = bars + (blk & 7) * 32;  // 8 shards x 32 blocks, 128B apart
        int v = __hip_atomic_fetch_add(sub, 1, __ATOMIC_ACQ_REL, __HIP_MEMORY_SCOPE_AGENT);
        if (v == (ph + 1) * 32 - 1) {
          int r = __hip_atomic_fetch_add(bars + 256, 1, __ATOMIC_ACQ_REL, __HIP_MEMORY_SCOPE_AGENT);
          if (r == (ph + 1) * 8 - 1)
            __hip_atomic_store(bars + 288, ph + 1, __ATOMIC_RELEASE, __HIP_MEMORY_SCOPE_AGENT);
        }
        while (__hip_atomic_load(bars + 288, __ATOMIC_ACQUIRE, __HIP_MEMORY_SCOPE_AGENT) <= ph)
          __builtin_amdgcn_s_sleep(2);
      }
      __syncthreads();
    }
  }
}

extern "C" void kernel_launch(void* const* d_in, const int* in_sizes, int n_in, void* d_out,
                              int out_size, void* d_ws, size_t ws_size, hipStream_t stream) {
  const float* input = (const float*)d_in[0];
  const float* w1 = (const float*)d_in[1];
  const float* b1 = (const float*)d_in[2];
  const float* w2 = (const float*)d_in[3];
  const float* b2 = (const float*)d_in[4];
  const float* fcw = (const float*)d_in[5];
  const float* fcb = (const float*)d_in[6];

  float* out = (float*)d_out;
  float* pose = out;
  float* h1o = out + 768;
  float* c1o = h1o + 131072;
  float* h2o = c1o + 131072;
  float* c2o = h2o + 262144;

  ushort_t* ws = (ushort_t*)d_ws;
  ushort_t* in1h0 = ws;
  ushort_t* in1h1 = ws + IN1SZ;
  ushort_t* in1l0 = ws + 2 * IN1SZ;
  ushort_t* in1l1 = ws + 3 * IN1SZ;
  ushort_t* i2b = ws + 4 * IN1SZ;
  ushort_t* in2h0 = i2b;
  ushort_t* in2h1 = i2b + IN2SZ;
  ushort_t* in2l0 = i2b + 2 * IN2SZ;
  ushort_t* in2l1 = i2b + 3 * IN2SZ;
  ushort_t* wp1 = ws + WP1OFF;
  ushort_t* wp2 = ws + WP2OFF;
  int* bars = (int*)(ws + BAROFF);

  hipMemsetAsync(ws, 0, (size_t)WP1OFF * 2, stream);                 // state buffers + borders
  hipMemsetAsync(bars, 0, 1280, stream);                             // barrier counters
  hipMemsetAsync(out + 768, 0, (size_t)786432 * 4, stream);          // h/c states = 0
  pack_kernel<<<339, 256, 0, stream>>>(w1, w2, fcb, input, pose, wp1, wp2, in1h0, in1l0);

  persist<<<256, 256, 0, stream>>>(input, wp1, wp2, b1, b2, fcw, pose, h1o, c1o, h2o, c2o,
                                   in1h0, in1h1, in1l0, in1l1, in2h0, in2h1, in2l0, in2l1, bars);
}

// Round 4
// 7342.425 us; speedup vs baseline: 1.1899x; 1.1899x over previous
//
#include <hip/hip_runtime.h>

typedef _Float16 f16;
typedef _Float16 f16x8 __attribute__((ext_vector_type(8)));
typedef float f32x4 __attribute__((ext_vector_type(4)));
typedef unsigned short ushort_t;
typedef unsigned int uint_t;

// ---------------------------------------------------------------------------
// PoseConvLSTM, single persistent kernel, 129 phases. Phase ph computes
// layer1[t=ph] ∥ layer2[t=ph-1]; device grid barrier between phases.
//
// Coherence scheme (no wbl2/inv!): all cross-block exchange buffers are
// accessed ONLY via relaxed agent-scope atomics (sc1: write-through /
// L2-bypass). Barrier = relaxed atomics + explicit s_waitcnt vmcnt(0).
// Weights/fcw stay warm in per-XCD L2 the whole kernel. c-states in regs.
//
// Exchange buffers (uint words = hi|lo f16 pair of 2 adjacent channels),
// padded-transposed [66][66][C/2]:
//   in1[par] C=48: c0-31=h1prev, c32-34=x[t], c35-47=0
//   in2[par] C=96: c0-31=h1[t],  c32-95=h2prev
// d_out (floats): pose[768] | h1[131072] | c1[131072] | h2[262144] | c2[262144]
// ---------------------------------------------------------------------------

#define IN1U 104544  // 66*66*24 uints
#define IN2U 209088  // 66*66*48 uints
#define WP1OFF 2509056  // ushort offset (= 4*IN1U+4*IN2U uints *2)
#define WP1SZ 147456
#define WP2OFF (WP1OFF + WP1SZ)
#define WP2SZ 442368
#define BAROFF (WP2OFF + WP2SZ)
#define NPH 129

__device__ __forceinline__ float sigm(float x) { return 1.0f / (1.0f + __expf(-x)); }
__device__ __forceinline__ ushort_t f2u(f16 v) { return __builtin_bit_cast(ushort_t, v); }
__device__ __forceinline__ f16x8 u2f(uint4 v) { return __builtin_bit_cast(f16x8, v); }
__device__ __forceinline__ uint_t loadc(const uint_t* p) {
  return __hip_atomic_load(p, __ATOMIC_RELAXED, __HIP_MEMORY_SCOPE_AGENT);
}
__device__ __forceinline__ void storec(uint_t* p, uint_t v) {
  __hip_atomic_store(p, v, __ATOMIC_RELAXED, __HIP_MEMORY_SCOPE_AGENT);
}

// ---- init: pack weights to MFMA A-frag order; pose=fc_b; stage x[0] ----
__global__ __launch_bounds__(256) void pack_kernel(const float* __restrict__ w1,
                                                   const float* __restrict__ w2,
                                                   const float* __restrict__ fcb,
                                                   const float* __restrict__ x0,
                                                   float* __restrict__ pose,
                                                   ushort_t* __restrict__ wp1,
                                                   ushort_t* __restrict__ wp2,
                                                   uint_t* __restrict__ i1h0,
                                                   uint_t* __restrict__ i1l0) {
  int i = blockIdx.x * 256 + threadIdx.x;
  if (i < 55296) {  // wp2 (in2 channels == original w2 channels)
    int lane = i & 63;
    int r0 = i >> 6;
    int hl = r0 & 1;
    int f = r0 >> 1;  // (mb*27+s)*8+mt
    int mt = f & 7;
    int sm = f >> 3;
    int s = sm % 27, mb = sm / 27;
    int m = mt * 16 + (lane & 15);
    int rg = mb * 128 + m;
    int h = rg >> 2, G = rg & 3;
    int orow = G * 64 + h;
    int tap = s / 3, cb = (s % 3) * 32;
    int cq = cb + (lane >> 4) * 8;
    for (int j = 0; j < 8; ++j) {
      float v = w2[(orow * 96 + cq + j) * 9 + tap];
      f16 vh = (f16)v;
      f16 vl = (f16)(v - (float)vh);
      wp2[(f * 2 + hl) * 512 + lane * 8 + j] = f2u(hl ? vl : vh);
    }
    return;
  }
  i -= 55296;
  if (i < 18432) {  // wp1: new channel map c<32->h1(c+3), c32-34->x(c-32), else 0
    int lane = i & 63;
    int r0 = i >> 6;
    int hl = r0 & 1;
    int f = r0 >> 1;  // (mb*18+s)*4+mt
    int mt = f & 3;
    int sm = f >> 2;
    int s = sm % 18, mb = sm / 18;
    int m = mt * 16 + (lane & 15);
    int rg = mb * 64 + m;
    int h = rg >> 2, G = rg & 3;
    int orow = G * 32 + h;
    int tap = s >> 1, cb = (s & 1) * 32;
    int cq = cb + (lane >> 4) * 8;
    for (int j = 0; j < 8; ++j) {
      int c = cq + j;
      float v = 0.f;
      if (c < 32) v = w1[(orow * 35 + (c + 3)) * 9 + tap];
      else if (c < 35) v = w1[(orow * 35 + (c - 32)) * 9 + tap];
      f16 vh = (f16)v;
      f16 vl = (f16)(v - (float)vh);
      wp1[(f * 2 + hl) * 512 + lane * 8 + j] = f2u(hl ? vl : vh);
    }
    return;
  }
  i -= 18432;
  if (i < 768) {
    pose[i] = fcb[i % 6];
    return;
  }
  i -= 768;
  if (i < 4096) {  // x[0] -> in1[0] packed channels 32-35
    int y = i >> 6, x = i & 63;
    float v0 = x0[i], v1 = x0[4096 + i], v2 = x0[8192 + i];
    f16 h0 = (f16)v0, h1 = (f16)v1, h2 = (f16)v2;
    f16 l0 = (f16)(v0 - (float)h0), l1 = (f16)(v1 - (float)h1), l2 = (f16)(v2 - (float)h2);
    int pb = ((y + 1) * 66 + (x + 1)) * 24;
    i1h0[pb + 16] = (uint_t)f2u(h0) | ((uint_t)f2u(h1) << 16);
    i1l0[pb + 16] = (uint_t)f2u(l0) | ((uint_t)f2u(l1) << 16);
    i1h0[pb + 17] = (uint_t)f2u(h2);
    i1l0[pb + 17] = (uint_t)f2u(l2);
  }
}

#define MFMA(a, b, c) __builtin_amdgcn_mfma_f32_16x16x32_f16((a), (b), (c), 0, 0, 0)

__global__ __launch_bounds__(256) void persist(
    const float* __restrict__ input, const ushort_t* __restrict__ wp1,
    const ushort_t* __restrict__ wp2, const float* __restrict__ b1g,
    const float* __restrict__ b2g, const float* __restrict__ fcw, float* __restrict__ pose,
    float* __restrict__ h1o, float* __restrict__ c1o, float* __restrict__ h2o,
    float* __restrict__ c2o, uint_t* i1h0, uint_t* i1h1, uint_t* i1l0, uint_t* i1l1,
    uint_t* i2h0, uint_t* i2h1, uint_t* i2l0, uint_t* i2l1, int* bars) {
  __shared__ __align__(16) ushort_t BH2[10400], BL2[10400];  // [pos100][104] (52 uints/row)
  __shared__ __align__(16) ushort_t BH1[7200], BL1[7200];    // [pos100][72]  (36 uints/row)
  __shared__ float red[4][6];
  __shared__ ushort_t ldspad[6144];

  const int tid = threadIdx.x, blk = blockIdx.x;
  if (tid == 0) ((volatile ushort_t*)ldspad)[0] = 0;
  const int lane = tid & 63, w = tid >> 6;
  const int q = lane >> 4, n = lane & 15, py = n >> 3, px = n & 7;
  const int mbx = blk & 3;
  const int nc = blk >> 2;
  const int Y0 = (nc >> 3) * 8, X0 = (nc & 7) * 8;
  const int mt0 = (w & 1) * 2;
  const int nt0 = (w >> 1) * 2;
  const int mtl1 = w & 1;

  uint_t* i1h[2] = {i1h0, i1h1};
  uint_t* i1l[2] = {i1l0, i1l1};
  uint_t* i2h[2] = {i2h0, i2h1};
  uint_t* i2l[2] = {i2l0, i2l1};

  const ushort_t *a2B0, *a2B1, *a1B;
  {
    int rt = mbx * 4 + mt0;
    a2B0 = wp2 + (size_t)((rt >> 3) * 216 + (rt & 7)) * 1024 + lane * 8;
    rt++;
    a2B1 = wp2 + (size_t)((rt >> 3) * 216 + (rt & 7)) * 1024 + lane * 8;
    rt = mbx * 2 + mtl1;
    a1B = wp1 + (size_t)((rt >> 2) * 72 + (rt & 3)) * 1024 + lane * 8;
  }
  const int bO20 = (((nt0 + 0) * 2 + py) * 10 + px) * 104 + q * 8;
  const int bO21 = (((nt0 + 1) * 2 + py) * 10 + px) * 104 + q * 8;
  const int bO10 = (((nt0 + 0) * 2 + py) * 10 + px) * 72 + q * 8;
  const int bO11 = (((nt0 + 1) * 2 + py) * 10 + px) * 72 + q * 8;

  float c2r[2][2] = {{0.f, 0.f}, {0.f, 0.f}};
  float c1r[2] = {0.f, 0.f};

  uint_t* uBH2 = (uint_t*)BH2;
  uint_t* uBL2 = (uint_t*)BL2;
  uint_t* uBH1 = (uint_t*)BH1;
  uint_t* uBL1 = (uint_t*)BL1;

  for (int ph = 0; ph < NPH; ++ph) {
    const int t1 = ph, t2 = ph - 1;
    const int p = ph & 1, pn = p ^ 1;
    const bool doL2 = (t2 >= 0), doL1 = (t1 < 128);

    // ---- stage halos into LDS via coherent uint loads ----
    if (doL2) {
      const uint_t* sh = i2h[pn];
      const uint_t* sl = i2l[pn];
      for (int i = tid; i < 4800; i += 256) {
        int pos = i / 48, cu = i % 48;
        int g = ((Y0 + pos / 10) * 66 + X0 + pos % 10) * 48 + cu;
        uBH2[pos * 52 + cu] = loadc(sh + g);
        uBL2[pos * 52 + cu] = loadc(sl + g);
      }
    }
    if (doL1) {
      const uint_t* sh = i1h[p];
      const uint_t* sl = i1l[p];
      for (int i = tid; i < 3200; i += 256) {
        int pos = i >> 5, cu = i & 31;
        int d = pos * 36 + cu;
        if (cu < 24) {
          int g = ((Y0 + pos / 10) * 66 + X0 + pos % 10) * 24 + cu;
          uBH1[d] = loadc(sh + g);
          uBL1[d] = loadc(sl + g);
        } else {  // channels 48..63 zero (A is zero there)
          uBH1[d] = 0u;
          uBL1[d] = 0u;
        }
      }
    }
    __syncthreads();

    // ---- layer 2: M=64, N=64, K=864 ----
    if (doL2) {
      f32x4 acc00 = {}, acc01 = {}, acc10 = {}, acc11 = {};
      uint4 Ab[2][2][2], Bb[2][2][2];
#pragma unroll
      for (int s0 = 0; s0 < 2; ++s0) {
        Ab[s0][0][0] = *(const uint4*)(a2B0 + s0 * 8192);
        Ab[s0][0][1] = *(const uint4*)(a2B0 + s0 * 8192 + 512);
        Ab[s0][1][0] = *(const uint4*)(a2B1 + s0 * 8192);
        Ab[s0][1][1] = *(const uint4*)(a2B1 + s0 * 8192 + 512);
      }
      Bb[0][0][0] = *(const uint4*)&BH2[bO20];
      Bb[0][0][1] = *(const uint4*)&BL2[bO20];
      Bb[0][1][0] = *(const uint4*)&BH2[bO21];
      Bb[0][1][1] = *(const uint4*)&BL2[bO21];
      int ty = 0, tx = 0, cc = 0;
      for (int s = 0; s < 27; ++s) {
        int ccn = cc + 1, tyn = ty, txn = tx;
        if (ccn == 3) {
          ccn = 0;
          txn++;
          if (txn == 3) { txn = 0; tyn++; }
        }
        uint4 a0h = Ab[s & 1][0][0], a0l = Ab[s & 1][0][1];
        uint4 a1h = Ab[s & 1][1][0], a1l = Ab[s & 1][1][1];
        uint4 b0h = Bb[s & 1][0][0], b0l = Bb[s & 1][0][1];
        uint4 b1h = Bb[s & 1][1][0], b1l = Bb[s & 1][1][1];
        if (s + 2 < 27) {
          Ab[s & 1][0][0] = *(const uint4*)(a2B0 + (s + 2) * 8192);
          Ab[s & 1][0][1] = *(const uint4*)(a2B0 + (s + 2) * 8192 + 512);
          Ab[s & 1][1][0] = *(const uint4*)(a2B1 + (s + 2) * 8192);
          Ab[s & 1][1][1] = *(const uint4*)(a2B1 + (s + 2) * 8192 + 512);
        }
        if (s + 1 < 27) {
          int d = tyn * 1040 + txn * 104 + ccn * 32;
          Bb[(s + 1) & 1][0][0] = *(const uint4*)&BH2[bO20 + d];
          Bb[(s + 1) & 1][0][1] = *(const uint4*)&BL2[bO20 + d];
          Bb[(s + 1) & 1][1][0] = *(const uint4*)&BH2[bO21 + d];
          Bb[(s + 1) & 1][1][1] = *(const uint4*)&BL2[bO21 + d];
        }
        f16x8 A0h = u2f(a0h), A0l = u2f(a0l), A1h = u2f(a1h), A1l = u2f(a1l);
        f16x8 B0h = u2f(b0h), B0l = u2f(b0l), B1h = u2f(b1h), B1l = u2f(b1l);
        acc00 = MFMA(A0h, B0h, acc00); acc00 = MFMA(A0h, B0l, acc00); acc00 = MFMA(A0l, B0h, acc00);
        acc01 = MFMA(A0h, B1h, acc01); acc01 = MFMA(A0h, B1l, acc01); acc01 = MFMA(A0l, B1h, acc01);
        acc10 = MFMA(A1h, B0h, acc10); acc10 = MFMA(A1h, B0l, acc10); acc10 = MFMA(A1l, B0h, acc10);
        acc11 = MFMA(A1h, B1h, acc11); acc11 = MFMA(A1h, B1l, acc11); acc11 = MFMA(A1l, B1h, acc11);
        ty = tyn; tx = txn; cc = ccn;
      }
      float p6[6] = {0, 0, 0, 0, 0, 0};
      uint_t* dh = i2h[p];
      uint_t* dl = i2l[p];
#pragma unroll
      for (int mi = 0; mi < 2; ++mi)
#pragma unroll
        for (int ni = 0; ni < 2; ++ni) {
          f32x4 a = mi ? (ni ? acc11 : acc10) : (ni ? acc01 : acc00);
          int h = mbx * 16 + (mt0 + mi) * 4 + q;
          int y = Y0 + (nt0 + ni) * 2 + py, x = X0 + px;
          float zi = a[0] + b2g[0 * 64 + h];
          float zf = a[1] + b2g[1 * 64 + h];
          float zo = a[2] + b2g[2 * 64 + h];
          float zg = a[3] + b2g[3 * 64 + h];
          float cold = c2r[mi][ni];
          float cn = sigm(zf) * cold + sigm(zi) * tanhf(zg);
          float hn = sigm(zo) * tanhf(cn);
          c2r[mi][ni] = cn;
          int cidx = h * 4096 + y * 64 + x;
#pragma unroll
          for (int j = 0; j < 6; ++j) p6[j] += hn * fcw[j * 262144 + cidx];
          f16 hh = (f16)hn;
          f16 hl = (f16)(hn - (float)hh);
          uint_t wv = (uint_t)f2u(hh) | ((uint_t)f2u(hl) << 16);
          uint_t pw = __shfl_xor((int)wv, 16, 64);
          int pb = ((y + 1) * 66 + (x + 1)) * 48 + 16 + (h >> 1);
          if (t2 < 127) {
            if ((q & 1) == 0) storec(dh + pb, (wv & 0xFFFFu) | (pw << 16));
            else              storec(dl + pb, (pw >> 16) | (wv & 0xFFFF0000u));
          } else {
            c2o[cidx] = cn;
            h2o[cidx] = hn;
          }
        }
#pragma unroll
      for (int j = 0; j < 6; ++j)
#pragma unroll
        for (int off = 32; off; off >>= 1) p6[j] += __shfl_xor(p6[j], off, 64);
      if (lane == 0)
#pragma unroll
        for (int j = 0; j < 6; ++j) red[w][j] = p6[j];
    }

    // ---- layer 1: M=32, N=64, K=576 ----
    if (doL1) {
      f32x4 acc0 = {}, acc1 = {};
      uint4 Ab[2][2], Bb[2][2][2];
#pragma unroll
      for (int s0 = 0; s0 < 2; ++s0) {
        Ab[s0][0] = *(const uint4*)(a1B + s0 * 4096);
        Ab[s0][1] = *(const uint4*)(a1B + s0 * 4096 + 512);
      }
      Bb[0][0][0] = *(const uint4*)&BH1[bO10];
      Bb[0][0][1] = *(const uint4*)&BL1[bO10];
      Bb[0][1][0] = *(const uint4*)&BH1[bO11];
      Bb[0][1][1] = *(const uint4*)&BL1[bO11];
      int ty = 0, tx = 0, cc = 0;
      for (int s = 0; s < 18; ++s) {
        int ccn = cc + 1, tyn = ty, txn = tx;
        if (ccn == 2) {
          ccn = 0;
          txn++;
          if (txn == 3) { txn = 0; tyn++; }
        }
        uint4 ah = Ab[s & 1][0], al = Ab[s & 1][1];
        uint4 b0h = Bb[s & 1][0][0], b0l = Bb[s & 1][0][1];
        uint4 b1h = Bb[s & 1][1][0], b1l = Bb[s & 1][1][1];
        if (s + 2 < 18) {
          Ab[s & 1][0] = *(const uint4*)(a1B + (s + 2) * 4096);
          Ab[s & 1][1] = *(const uint4*)(a1B + (s + 2) * 4096 + 512);
        }
        if (s + 1 < 18) {
          int d = tyn * 720 + txn * 72 + ccn * 32;
          Bb[(s + 1) & 1][0][0] = *(const uint4*)&BH1[bO10 + d];
          Bb[(s + 1) & 1][0][1] = *(const uint4*)&BL1[bO10 + d];
          Bb[(s + 1) & 1][1][0] = *(const uint4*)&BH1[bO11 + d];
          Bb[(s + 1) & 1][1][1] = *(const uint4*)&BL1[bO11 + d];
        }
        f16x8 Ah = u2f(ah), Al = u2f(al);
        f16x8 B0h = u2f(b0h), B0l = u2f(b0l), B1h = u2f(b1h), B1l = u2f(b1l);
        acc0 = MFMA(Ah, B0h, acc0); acc0 = MFMA(Ah, B0l, acc0); acc0 = MFMA(Al, B0h, acc0);
        acc1 = MFMA(Ah, B1h, acc1); acc1 = MFMA(Ah, B1l, acc1); acc1 = MFMA(Al, B1h, acc1);
        ty = tyn; tx = txn; cc = ccn;
      }
      uint_t* d2h = i2h[p];
      uint_t* d2l = i2l[p];
      uint_t* d1h = i1h[pn];
      uint_t* d1l = i1l[pn];
#pragma unroll
      for (int ni = 0; ni < 2; ++ni) {
        f32x4 a = ni ? acc1 : acc0;
        int h = mbx * 8 + mtl1 * 4 + q;
        int y = Y0 + (nt0 + ni) * 2 + py, x = X0 + px;
        float zi = a[0] + b1g[0 * 32 + h];
        float zf = a[1] + b1g[1 * 32 + h];
        float zo = a[2] + b1g[2 * 32 + h];
        float zg = a[3] + b1g[3 * 32 + h];
        float cold = c1r[ni];
        float cn = sigm(zf) * cold + sigm(zi) * tanhf(zg);
        float hn = sigm(zo) * tanhf(cn);
        c1r[ni] = cn;
        f16 hh = (f16)hn;
        f16 hl = (f16)(hn - (float)hh);
        uint_t wv = (uint_t)f2u(hh) | ((uint_t)f2u(hl) << 16);
        uint_t pw = __shfl_xor((int)wv, 16, 64);
        uint_t hw = (wv & 0xFFFFu) | (pw << 16);
        uint_t lw = (pw >> 16) | (wv & 0xFFFF0000u);
        int pix = (y + 1) * 66 + (x + 1);
        if ((q & 1) == 0) storec(d2h + pix * 48 + (h >> 1), hw);
        else              storec(d2l + pix * 48 + (h >> 1), lw);
        if (t1 < 127) {
          if ((q & 1) == 0) storec(d1h + pix * 24 + (h >> 1), hw);
          else              storec(d1l + pix * 24 + (h >> 1), lw);
        }
        if (t1 == 127) {
          int cidx = h * 4096 + y * 64 + x;
          c1o[cidx] = cn;
          h1o[cidx] = hn;
        }
      }
      if (mbx == 0 && t1 < 127 && tid < 64) {  // stage x[t1+1] -> in1[pn] c32-35
        const float* xn = input + (size_t)(t1 + 1) * 12288;
        int y = Y0 + (tid >> 3), x = X0 + (tid & 7);
        int gi = y * 64 + x;
        float v0 = xn[gi], v1 = xn[4096 + gi], v2 = xn[8192 + gi];
        f16 h0 = (f16)v0, h1 = (f16)v1, h2 = (f16)v2;
        f16 l0 = (f16)(v0 - (float)h0), l1 = (f16)(v1 - (float)h1), l2 = (f16)(v2 - (float)h2);
        int pb = ((y + 1) * 66 + (x + 1)) * 24;
        storec(d1h + pb + 16, (uint_t)f2u(h0) | ((uint_t)f2u(h1) << 16));
        storec(d1l + pb + 16, (uint_t)f2u(l0) | ((uint_t)f2u(l1) << 16));
        storec(d1h + pb + 17, (uint_t)f2u(h2));
        storec(d1l + pb + 17, (uint_t)f2u(l2));
      }
    }

    // ---- drain + pose + relaxed grid barrier ----
    asm volatile("s_waitcnt vmcnt(0)" ::: "memory");
    __syncthreads();
    if (doL2 && tid < 6)
      atomicAdd(pose + t2 * 6 + tid, red[0][tid] + red[1][tid] + red[2][tid] + red[3][tid]);
    if (ph + 1 < NPH) {
      if (tid == 0) {
        int* sub = bars + (blk & 7) * 32;
        int v = __hip_atomic_fetch_add(sub, 1, __ATOMIC_RELAXED, __HIP_MEMORY_SCOPE_AGENT);
        if (v == (ph + 1) * 32 - 1) {
          int r = __hip_atomic_fetch_add(bars + 256, 1, __ATOMIC_RELAXED, __HIP_MEMORY_SCOPE_AGENT);
          if (r == (ph + 1) * 8 - 1)
            __hip_atomic_store(bars + 288, ph + 1, __ATOMIC_RELAXED, __HIP_MEMORY_SCOPE_AGENT);
        }
        while (__hip_atomic_load(bars + 288, __ATOMIC_RELAXED, __HIP_MEMORY_SCOPE_AGENT) <= ph)
          __builtin_amdgcn_s_sleep(1);
      }
      __syncthreads();
      asm volatile("" ::: "memory");
    }
  }
}

extern "C" void kernel_launch(void* const* d_in, const int* in_sizes, int n_in, void* d_out,
                              int out_size, void* d_ws, size_t ws_size, hipStream_t stream) {
  const float* input = (const float*)d_in[0];
  const float* w1 = (const float*)d_in[1];
  const float* b1 = (const float*)d_in[2];
  const float* w2 = (const float*)d_in[3];
  const float* b2 = (const float*)d_in[4];
  const float* fcw = (const float*)d_in[5];
  const float* fcb = (const float*)d_in[6];

  float* out = (float*)d_out;
  float* pose = out;
  float* h1o = out + 768;
  float* c1o = h1o + 131072;
  float* h2o = c1o + 131072;
  float* c2o = h2o + 262144;

  uint_t* W = (uint_t*)d_ws;
  uint_t* i1h0 = W;
  uint_t* i1h1 = W + IN1U;
  uint_t* i1l0 = W + 2 * IN1U;
  uint_t* i1l1 = W + 3 * IN1U;
  uint_t* B2 = W + 4 * IN1U;
  uint_t* i2h0 = B2;
  uint_t* i2h1 = B2 + IN2U;
  uint_t* i2l0 = B2 + 2 * IN2U;
  uint_t* i2l1 = B2 + 3 * IN2U;
  ushort_t* wsu = (ushort_t*)d_ws;
  ushort_t* wp1 = wsu + WP1OFF;
  ushort_t* wp2 = wsu + WP2OFF;
  int* bars = (int*)(wsu + BAROFF);

  hipMemsetAsync(d_ws, 0, (size_t)WP1OFF * 2, stream);  // zero exchange buffers (t=0 state + borders)
  hipMemsetAsync(bars, 0, 1280, stream);                // barrier counters
  pack_kernel<<<307, 256, 0, stream>>>(w1, w2, fcb, input, pose, wp1, wp2, i1h0, i1l0);

  persist<<<256, 256, 0, stream>>>(input, wp1, wp2, b1, b2, fcw, pose, h1o, c1o, h2o, c2o,
                                   i1h0, i1h1, i1l0, i1l1, i2h0, i2h1, i2l0, i2l1, bars);
}